// Round 11
// baseline (121.927 us; speedup 1.0000x reference)
//
#include <hip/hip_runtime.h>
#include <hip/hip_bf16.h>

// Grid_INR2D round 11: 64-VGPR diet -> 8 waves/SIMD occupancy step.
//  Rounds 7-10: four allocator collapses at the 128-VGPR edge. New strategy:
//  genuinely fit the 64-VGPR step instead of fighting the 128 boundary.
//   - NO persistent weight/bias regs: per-batch frags from LDS; b2 via
//     transient f32x4 global loads (L1-hot); b3 in SGPRs.
//   - LDS frag table 22 -> 14 frags (14KB): w1-local frags are prologue-only
//     -> loaded from global into transient regs for the 8 c1base MFMAs.
//     14KB * 8 blocks = 112KB < 160KB -> LDS admits 8 blocks/CU.
//   - launch_bounds(256,8); grid (1024,2) = 2048 blocks x 4 batches
//     -> 8 resident blocks/CU = 32 waves/CU (occupancy 2x round 6).
//  Persistent ~32 VGPR (c1base16+raw8+addr), peak ~58. Per-batch arithmetic
//  order identical to rounds 5-10 -> absmax must stay 0.0078125.
//  GATE: dur >= 40us means spill collapse -> revert to round-6 source.
// Fragment identity (validated rounds 3-10):
//   A: row=lane&15, k=4*(lane>>4)+(e&3)+16*(e>>2); B: col=lane&15, same k;
//   C/D: col=lane&15, row=4*(lane>>4)+reg  ==> C-frag of layer n is B-frag
//   of layer n+1 per-lane: B[kb].e = bf16(relu(C[2kb+(e>=4)].reg[e&3])).

typedef float f32x4 __attribute__((ext_vector_type(4)));
typedef short s16x8 __attribute__((ext_vector_type(8)));

#define MFMA16(a, b, c) __builtin_amdgcn_mfma_f32_16x16x32_bf16((a), (b), (c), 0, 0, 0)

__device__ __forceinline__ short bfbits(float f) {   // RNE via HW cvt
    return __builtin_bit_cast(short, __float2bfloat16(f));
}

__device__ __forceinline__ s16x8 pack_relu(const f32x4 lo, const f32x4 hi) {
    s16x8 r;
#pragma unroll
    for (int e = 0; e < 4; ++e) {
        r[e]     = bfbits(fmaxf(lo[e], 0.0f));
        r[e + 4] = bfbits(fmaxf(hi[e], 0.0f));
    }
    return r;
}

// LDS frag table (per-batch frags only):
//   fid 0..3 = w1-feat[mt], 4..11 = w2[2mt+kb], 12..13 = w3[kb]
#define NFRAG 14

__global__ __launch_bounds__(256, 8) void grid_inr_mfma(
    const float* __restrict__ feat,
    const float* __restrict__ g0, const float* __restrict__ g1,
    const float* __restrict__ g2, const float* __restrict__ g3,
    const float* __restrict__ w1, const float* __restrict__ b1,
    const float* __restrict__ w2, const float* __restrict__ b2,
    const float* __restrict__ w3, const float* __restrict__ b3,
    float* __restrict__ out)
{
    __shared__ __align__(16) short lds_w[NFRAG * 64 * 8];

    const int lane  = threadIdx.x & 63;
    const int col   = lane & 15;    // A row / B col / pixel-in-tile
    const int lrow  = lane >> 4;    // k-group
    const int wv    = threadIdx.x >> 6;
    const int p     = blockIdx.x * 64 + wv * 16 + col;   // this lane's pixel
    const int b0    = blockIdx.y * 4;                    // first of 4 batches

    // ---------------- stage 14 per-batch A-frags into LDS -------------------
    {
        const int cs = lane, c15 = lane & 15, r4 = lane >> 4;
#pragma unroll 1
        for (int fid = threadIdx.x >> 6; fid < NFRAG; fid += 4) {
            const float* src;
            if (fid < 4) {                       // w1-feat (kb=0 slice)
                src = w1 + (16 * fid + c15) * 96 + 4 * r4;
            } else if (fid < 12) {               // w2
                const int f = fid - 4, mt = f >> 1, kb = f & 1;
                src = w2 + (16 * mt + c15) * 64 + 32 * kb + 4 * r4;
            } else {                             // w3 (rows 3..15 junk, unused)
                const int kb = fid - 12;
                const int row3 = (c15 < 3) ? c15 : 2;
                src = w3 + row3 * 64 + 32 * kb + 4 * r4;
            }
            s16x8 frag;
#pragma unroll
            for (int e = 0; e < 8; ++e)
                frag[e] = bfbits(src[(e & 3) + 16 * (e >> 2)]);
            *(s16x8*)&lds_w[(fid * 64 + cs) * 8] = frag;
        }
    }

    const float b3s0 = b3[0], b3s1 = b3[1], b3s2 = b3[2];  // uniform -> SGPR

    // ---------------- grid-sample -> localB[2] (B-frags, k=local ch) --------
    s16x8 localB[2];
    {
        const float* gs[4] = {g0, g1, g2, g3};
        const int    gn[4] = {32, 64, 128, 256};
        const int px = p & 255;
        const int py = p >> 8;
#pragma unroll
        for (int lv = 0; lv < 4; ++lv) {
            const int G = gn[lv];
            const float ix = (float)((2 * px + 1) * (G - 1)) * (1.0f / 512.0f);
            const float iy = (float)((2 * py + 1) * (G - 1)) * (1.0f / 512.0f);
            int ix0 = (int)ix;
            int iy0 = (int)iy;
            if (ix0 > G - 1) ix0 = G - 1;
            if (iy0 > G - 1) iy0 = G - 1;
            const int ix1 = (ix0 + 1 < G - 1) ? (ix0 + 1) : (G - 1);
            const int iy1 = (iy0 + 1 < G - 1) ? (iy0 + 1) : (G - 1);
            const float wx = ix - (float)ix0;
            const float wy = iy - (float)iy0;
            const float w00 = (1.0f - wy) * (1.0f - wx);
            const float w01 = (1.0f - wy) * wx;
            const float w10 = wy * (1.0f - wx);
            const float w11 = wy * wx;
            const int o00 = iy0 * G + ix0;
            const int o01 = iy0 * G + ix1;
            const int o10 = iy1 * G + ix0;
            const int o11 = iy1 * G + ix1;
            const float* g = gs[lv];
            const int GG = G * G;
#pragma unroll
            for (int j = 0; j < 4; ++j) {
                const float* gc = g + (4 * lrow + j) * GG;
                const float v = gc[o00] * w00 + gc[o01] * w01 +
                                gc[o10] * w10 + gc[o11] * w11;
                localB[lv >> 1][(lv & 1) * 4 + j] = bfbits(v);
            }
        }
    }

    // ---- c1base[mt] = b1 + W1[:,32:96].local ; w1-local frags from GLOBAL --
    // (same bf16 values and MFMA order as the LDS path of rounds 5-10.)
    f32x4 c1base[4];
#pragma unroll
    for (int mt = 0; mt < 4; ++mt) {
        c1base[mt] = *(const f32x4*)(b1 + 16 * mt + 4 * lrow);
#pragma unroll
        for (int kb = 1; kb <= 2; ++kb) {
            const float* wr = w1 + (16 * mt + col) * 96 + 32 * kb + 4 * lrow;
            const f32x4 lo = *(const f32x4*)(wr);        // e=0..3
            const f32x4 hi = *(const f32x4*)(wr + 16);   // e=4..7
            s16x8 frag;
#pragma unroll
            for (int e = 0; e < 4; ++e) {
                frag[e]     = bfbits(lo[e]);
                frag[e + 4] = bfbits(hi[e]);
            }
            c1base[mt] = MFMA16(frag, localB[kb - 1], c1base[mt]);
        }
    }
    // localB dead from here.

    // issue first batch's feat loads before the barrier
    float raw[8];
#pragma unroll
    for (int e = 0; e < 8; ++e) {
        const int fc = 4 * lrow + (e & 3) + 16 * (e >> 2);
        raw[e] = feat[(((b0 << 5) | fc) << 16) + p];
    }

    __syncthreads();   // LDS frag table ready

    const short* lw = lds_w + lane * 8;      // per-lane base; fid via offset
#define LDSFRAG(fid) (*(const s16x8*)(lw + (fid) * 64 * 8))

    // ---------------- per-batch MLP (4 batches, depth-1 prefetch) -----------
#pragma unroll 1
    for (int bi = 0; bi < 4; ++bi) {
        const int b = b0 + bi;

        s16x8 ff;
#pragma unroll
        for (int e = 0; e < 8; ++e) ff[e] = bfbits(raw[e]);
        if (bi < 3) {
#pragma unroll
            for (int e = 0; e < 8; ++e) {
                const int fc = 4 * lrow + (e & 3) + 16 * (e >> 2);
                raw[e] = feat[((((b + 1) << 5) | fc) << 16) + p];
            }
        }

        // layer 1: single MFMA per mtile, seeded from batch-invariant base
        f32x4 c1[4];
#pragma unroll
        for (int mt = 0; mt < 4; ++mt)
            c1[mt] = MFMA16(LDSFRAG(mt), ff, c1base[mt]);

        s16x8 h1b0 = pack_relu(c1[0], c1[1]);
        s16x8 h1b1 = pack_relu(c1[2], c1[3]);

        // layer 2: b2 re-read per batch (transient, L1-hot 256B table)
        f32x4 c2[4];
#pragma unroll
        for (int mt = 0; mt < 4; ++mt) {
            c2[mt] = *(const f32x4*)(b2 + 16 * mt + 4 * lrow);
            c2[mt] = MFMA16(LDSFRAG(4 + mt * 2),     h1b0, c2[mt]);
            c2[mt] = MFMA16(LDSFRAG(4 + mt * 2 + 1), h1b1, c2[mt]);
        }
        s16x8 h2b0 = pack_relu(c2[0], c2[1]);
        s16x8 h2b1 = pack_relu(c2[2], c2[3]);

        // layer 3 (rows 0..2 valid) + store
        f32x4 c3 = {0.f, 0.f, 0.f, 0.f};
        c3 = MFMA16(LDSFRAG(12), h2b0, c3);
        c3 = MFMA16(LDSFRAG(13), h2b1, c3);

        if (lrow == 0) {
            out[((b * 3 + 0) << 16) + p] = c3[0] + b3s0;
            out[((b * 3 + 1) << 16) + p] = c3[1] + b3s1;
            out[((b * 3 + 2) << 16) + p] = c3[2] + b3s2;
        }
    }
#undef LDSFRAG
}

extern "C" void kernel_launch(void* const* d_in, const int* in_sizes, int n_in,
                              void* d_out, int out_size, void* d_ws, size_t ws_size,
                              hipStream_t stream) {
    const float* feat = (const float*)d_in[0];
    const float* g0   = (const float*)d_in[1];
    const float* g1   = (const float*)d_in[2];
    const float* g2   = (const float*)d_in[3];
    const float* g3   = (const float*)d_in[4];
    const float* w1   = (const float*)d_in[5];
    const float* b1   = (const float*)d_in[6];
    const float* w2   = (const float*)d_in[7];
    const float* b2   = (const float*)d_in[8];
    const float* w3   = (const float*)d_in[9];
    const float* b3   = (const float*)d_in[10];

    // x: 65536 px / 64 px-per-block = 1024;  y: 2 batch-slices (4 b each).
    // 2048 blocks, 14KB LDS, <=64 VGPR -> 8 resident blocks/CU (32 waves/CU).
    dim3 grid(1024, 2);
    grid_inr_mfma<<<grid, 256, 0, stream>>>(
        feat, g0, g1, g2, g3, w1, b1, w2, b2, w3, b3, (float*)d_out);
}

// Round 12
// 59.704 us; speedup vs baseline: 2.0422x; 2.0422x over previous
//
#include <hip/hip_runtime.h>
#include <hip/hip_bf16.h>

// Grid_INR2D round 12: two-kernel split to decouple register pressure.
//  Five allocator collapses (r7-r11) prove the FUSED kernel is register-
//  saturated: grid-sample prologue + c1base + batch MLP only coexist at
//  (256,4)/128-cap with zero slack. Split via d_ws:
//   K1: batch-invariant precompute (grid-sample -> c1base -> ws) +
//       pre-swizzled bf16 weight-frag table (block 0). (256,4), ~80 live.
//   K2: pure MLP, grid (1024,4) x 2 batches = 4096 blocks. Stages the 16KB
//       frag table ws->LDS (coalesced), loads c1base (coalesced f32x4),
//       runs 2 bodies. (256,6) cap~85, peak live ~70 -> real slack.
//       6 resident blocks/CU, 16 assigned -> queue depth 2.7x fills the
//       latency bubbles that grid==residency never could.
//  Identical bf16 values + MFMA order as rounds 5-11; c1base round-trips
//  ws as exact f32 -> absmax must stay exactly 0.0078125.
//  Host falls back to the round-6 kernel (28.8us verified) if ws_size is
//  too small for table+c1base (16,793,600 B).
// Fragment identity (validated rounds 3-11):
//   A: row=lane&15, k=4*(lane>>4)+(e&3)+16*(e>>2); B: col=lane&15, same k;
//   C/D: col=lane&15, row=4*(lane>>4)+reg  ==> C-frag of layer n is B-frag
//   of layer n+1 per-lane: B[kb].e = bf16(relu(C[2kb+(e>=4)].reg[e&3])).

typedef float f32x4 __attribute__((ext_vector_type(4)));
typedef short s16x8 __attribute__((ext_vector_type(8)));

#define MFMA16(a, b, c) __builtin_amdgcn_mfma_f32_16x16x32_bf16((a), (b), (c), 0, 0, 0)

__device__ __forceinline__ short bfbits(float f) {   // RNE via HW cvt
    return __builtin_bit_cast(short, __float2bfloat16(f));
}

__device__ __forceinline__ s16x8 pack_relu(const f32x4 lo, const f32x4 hi) {
    s16x8 r;
#pragma unroll
    for (int e = 0; e < 4; ++e) {
        r[e]     = bfbits(fmaxf(lo[e], 0.0f));
        r[e + 4] = bfbits(fmaxf(hi[e], 0.0f));
    }
    return r;
}

// ws layout: [0, 16384) bf16 frag table (14 frags x 1KB, padded to 16KB);
//            [16384, 16384+16MB) c1base, f32x4 granule (mt*4+lrow)*65536+p.
#define WS_TAB_BYTES 16384
#define NFRAG 14
// frag table ids: 0..3 = w1-feat[mt], 4..11 = w2[2mt+kb], 12..13 = w3[kb]

// ---------------------------------------------------------------- kernel 1
__global__ __launch_bounds__(256, 4) void k1_precomp(
    const float* __restrict__ g0, const float* __restrict__ g1,
    const float* __restrict__ g2, const float* __restrict__ g3,
    const float* __restrict__ w1, const float* __restrict__ b1,
    const float* __restrict__ w2, const float* __restrict__ w3,
    void* __restrict__ ws)
{
    const int lane  = threadIdx.x & 63;
    const int col   = lane & 15;
    const int lrow  = lane >> 4;
    const int wv    = threadIdx.x >> 6;
    const int p     = blockIdx.x * 64 + wv * 16 + col;

    // ---- block 0: build the pre-swizzled bf16 weight frag table in ws ----
    if (blockIdx.x == 0) {
        short* wtab = (short*)ws;
#pragma unroll 1
        for (int i = threadIdx.x; i < NFRAG * 64; i += 256) {
            const int fid = i >> 6, l = i & 63;
            const int c15 = l & 15, r4 = l >> 4;
            const float* src;
            if (fid < 4) {                       // w1-feat (kb=0 slice)
                src = w1 + (16 * fid + c15) * 96 + 4 * r4;
            } else if (fid < 12) {               // w2
                const int f = fid - 4, mt = f >> 1, kb = f & 1;
                src = w2 + (16 * mt + c15) * 64 + 32 * kb + 4 * r4;
            } else {                             // w3 (rows 3..15 junk)
                const int kb = fid - 12;
                const int row3 = (c15 < 3) ? c15 : 2;
                src = w3 + row3 * 64 + 32 * kb + 4 * r4;
            }
            s16x8 frag;
#pragma unroll
            for (int e = 0; e < 8; ++e)
                frag[e] = bfbits(src[(e & 3) + 16 * (e >> 2)]);
            *(s16x8*)&wtab[i * 8] = frag;
        }
    }

    // ---- grid-sample -> localB[2] (B-frags) -------------------------------
    s16x8 localB[2];
    {
        const float* gs[4] = {g0, g1, g2, g3};
        const int    gn[4] = {32, 64, 128, 256};
        const int px = p & 255;
        const int py = p >> 8;
#pragma unroll
        for (int lv = 0; lv < 4; ++lv) {
            const int G = gn[lv];
            const float ix = (float)((2 * px + 1) * (G - 1)) * (1.0f / 512.0f);
            const float iy = (float)((2 * py + 1) * (G - 1)) * (1.0f / 512.0f);
            int ix0 = (int)ix;
            int iy0 = (int)iy;
            if (ix0 > G - 1) ix0 = G - 1;
            if (iy0 > G - 1) iy0 = G - 1;
            const int ix1 = (ix0 + 1 < G - 1) ? (ix0 + 1) : (G - 1);
            const int iy1 = (iy0 + 1 < G - 1) ? (iy0 + 1) : (G - 1);
            const float wx = ix - (float)ix0;
            const float wy = iy - (float)iy0;
            const float w00 = (1.0f - wy) * (1.0f - wx);
            const float w01 = (1.0f - wy) * wx;
            const float w10 = wy * (1.0f - wx);
            const float w11 = wy * wx;
            const int o00 = iy0 * G + ix0;
            const int o01 = iy0 * G + ix1;
            const int o10 = iy1 * G + ix0;
            const int o11 = iy1 * G + ix1;
            const float* g = gs[lv];
            const int GG = G * G;
#pragma unroll
            for (int j = 0; j < 4; ++j) {
                const float* gc = g + (4 * lrow + j) * GG;
                const float v = gc[o00] * w00 + gc[o01] * w01 +
                                gc[o10] * w10 + gc[o11] * w11;
                localB[lv >> 1][(lv & 1) * 4 + j] = bfbits(v);
            }
        }
    }

    // ---- c1base[mt] = b1 + W1[:,32:96].local (w1-local frags transient) ----
    f32x4 c1base[4];
#pragma unroll
    for (int mt = 0; mt < 4; ++mt) {
        c1base[mt] = *(const f32x4*)(b1 + 16 * mt + 4 * lrow);
#pragma unroll
        for (int kb = 1; kb <= 2; ++kb) {
            const float* wr = w1 + (16 * mt + col) * 96 + 32 * kb + 4 * lrow;
            const f32x4 lo = *(const f32x4*)(wr);
            const f32x4 hi = *(const f32x4*)(wr + 16);
            s16x8 frag;
#pragma unroll
            for (int e = 0; e < 4; ++e) {
                frag[e]     = bfbits(lo[e]);
                frag[e + 4] = bfbits(hi[e]);
            }
            c1base[mt] = MFMA16(frag, localB[kb - 1], c1base[mt]);
        }
    }

    // ---- store c1base: 4 x (16 lanes x 16B = 256B coalesced) per wave ------
    f32x4* wsc = (f32x4*)((char*)ws + WS_TAB_BYTES);
#pragma unroll
    for (int mt = 0; mt < 4; ++mt)
        wsc[(mt * 4 + lrow) * 65536 + p] = c1base[mt];
}

// ---------------------------------------------------------------- kernel 2
__global__ __launch_bounds__(256, 6) void k2_mlp(
    const float* __restrict__ feat,
    const float* __restrict__ b2, const float* __restrict__ b3,
    const void* __restrict__ ws, float* __restrict__ out)
{
    __shared__ __align__(16) short lds_w[WS_TAB_BYTES / 2];

    const int lane  = threadIdx.x & 63;
    const int col   = lane & 15;
    const int lrow  = lane >> 4;
    const int wv    = threadIdx.x >> 6;
    const int p     = blockIdx.x * 64 + wv * 16 + col;
    const int bA    = blockIdx.y * 2;
    const int bB    = bA + 1;

    // issue all independent loads up front: table, c1base, both feat sets
    const f32x4* wtab = (const f32x4*)ws;                  // 16B granules
    const f32x4 s0 = wtab[threadIdx.x];
    const f32x4 s1 = wtab[threadIdx.x + 256];
    const f32x4 s2 = wtab[threadIdx.x + 512];
    const f32x4 s3 = wtab[threadIdx.x + 768];

    const f32x4* wsc = (const f32x4*)((const char*)ws + WS_TAB_BYTES);
    f32x4 c1base[4];
#pragma unroll
    for (int mt = 0; mt < 4; ++mt)
        c1base[mt] = wsc[(mt * 4 + lrow) * 65536 + p];

    float rawA[8], rawB[8];
#pragma unroll
    for (int e = 0; e < 8; ++e) {
        const int fc = 4 * lrow + (e & 3) + 16 * (e >> 2);
        rawA[e] = feat[(((bA << 5) | fc) << 16) + p];
        rawB[e] = feat[(((bB << 5) | fc) << 16) + p];
    }
    const float b3s0 = b3[0], b3s1 = b3[1], b3s2 = b3[2];  // uniform s_loads

    // stage table to LDS (linear copy, coalesced)
    f32x4* lw4 = (f32x4*)lds_w;
    lw4[threadIdx.x]       = s0;
    lw4[threadIdx.x + 256] = s1;
    lw4[threadIdx.x + 512] = s2;
    lw4[threadIdx.x + 768] = s3;
    __syncthreads();

    const short* lwp = lds_w + lane * 8;
#define LDSFRAG(fid) (*(const s16x8*)(lwp + (fid) * 64 * 8))

    // ---------------- body A (batch bA) ------------------------------------
    {
        s16x8 ff;
#pragma unroll
        for (int e = 0; e < 8; ++e) ff[e] = bfbits(rawA[e]);
        f32x4 c1[4];
#pragma unroll
        for (int mt = 0; mt < 4; ++mt)
            c1[mt] = MFMA16(LDSFRAG(mt), ff, c1base[mt]);
        const s16x8 h1b0 = pack_relu(c1[0], c1[1]);
        const s16x8 h1b1 = pack_relu(c1[2], c1[3]);
        f32x4 c2[4];
#pragma unroll
        for (int mt = 0; mt < 4; ++mt) {
            c2[mt] = *(const f32x4*)(b2 + 16 * mt + 4 * lrow);
            c2[mt] = MFMA16(LDSFRAG(4 + mt * 2),     h1b0, c2[mt]);
            c2[mt] = MFMA16(LDSFRAG(4 + mt * 2 + 1), h1b1, c2[mt]);
        }
        const s16x8 h2b0 = pack_relu(c2[0], c2[1]);
        const s16x8 h2b1 = pack_relu(c2[2], c2[3]);
        f32x4 c3 = {0.f, 0.f, 0.f, 0.f};
        c3 = MFMA16(LDSFRAG(12), h2b0, c3);
        c3 = MFMA16(LDSFRAG(13), h2b1, c3);
        if (lrow == 0) {
            out[((bA * 3 + 0) << 16) + p] = c3[0] + b3s0;
            out[((bA * 3 + 1) << 16) + p] = c3[1] + b3s1;
            out[((bA * 3 + 2) << 16) + p] = c3[2] + b3s2;
        }
    }
    // ---------------- body B (batch bB) ------------------------------------
    {
        s16x8 ff;
#pragma unroll
        for (int e = 0; e < 8; ++e) ff[e] = bfbits(rawB[e]);
        f32x4 c1[4];
#pragma unroll
        for (int mt = 0; mt < 4; ++mt)
            c1[mt] = MFMA16(LDSFRAG(mt), ff, c1base[mt]);
        const s16x8 h1b0 = pack_relu(c1[0], c1[1]);
        const s16x8 h1b1 = pack_relu(c1[2], c1[3]);
        f32x4 c2[4];
#pragma unroll
        for (int mt = 0; mt < 4; ++mt) {
            c2[mt] = *(const f32x4*)(b2 + 16 * mt + 4 * lrow);
            c2[mt] = MFMA16(LDSFRAG(4 + mt * 2),     h1b0, c2[mt]);
            c2[mt] = MFMA16(LDSFRAG(4 + mt * 2 + 1), h1b1, c2[mt]);
        }
        const s16x8 h2b0 = pack_relu(c2[0], c2[1]);
        const s16x8 h2b1 = pack_relu(c2[2], c2[3]);
        f32x4 c3 = {0.f, 0.f, 0.f, 0.f};
        c3 = MFMA16(LDSFRAG(12), h2b0, c3);
        c3 = MFMA16(LDSFRAG(13), h2b1, c3);
        if (lrow == 0) {
            out[((bB * 3 + 0) << 16) + p] = c3[0] + b3s0;
            out[((bB * 3 + 1) << 16) + p] = c3[1] + b3s1;
            out[((bB * 3 + 2) << 16) + p] = c3[2] + b3s2;
        }
    }
#undef LDSFRAG
}

// ------------------------------------------- fallback: round-6 kernel (28.8us)
#define R6NFRAG 22
__global__ __launch_bounds__(256, 4) void grid_inr_r6(
    const float* __restrict__ feat,
    const float* __restrict__ g0, const float* __restrict__ g1,
    const float* __restrict__ g2, const float* __restrict__ g3,
    const float* __restrict__ w1, const float* __restrict__ b1,
    const float* __restrict__ w2, const float* __restrict__ b2,
    const float* __restrict__ w3, const float* __restrict__ b3,
    float* __restrict__ out)
{
    __shared__ __align__(16) short lds_w[R6NFRAG * 64 * 8];
    const int lane  = threadIdx.x & 63;
    const int col   = lane & 15;
    const int lrow  = lane >> 4;
    const int wv    = threadIdx.x >> 6;
    const int p     = blockIdx.x * 64 + wv * 16 + col;
    {
        const int cs = lane, c15 = lane & 15, r4 = lane >> 4;
#pragma unroll 1
        for (int fid = threadIdx.x >> 6; fid < R6NFRAG; fid += 4) {
            const float* src;
            if (fid < 12) {
                const int mt = fid / 3, kb = fid - 3 * mt;
                src = w1 + (16 * mt + c15) * 96 + 32 * kb + 4 * r4;
            } else if (fid < 20) {
                const int f = fid - 12, mt = f >> 1, kb = f & 1;
                src = w2 + (16 * mt + c15) * 64 + 32 * kb + 4 * r4;
            } else {
                const int kb = fid - 20;
                const int row3 = (c15 < 3) ? c15 : 2;
                src = w3 + row3 * 64 + 32 * kb + 4 * r4;
            }
            s16x8 frag;
#pragma unroll
            for (int e = 0; e < 8; ++e)
                frag[e] = bfbits(src[(e & 3) + 16 * (e >> 2)]);
            *(s16x8*)&lds_w[(fid * 64 + cs) * 8] = frag;
        }
    }
    f32x4 b1f[4], b2f[4];
#pragma unroll
    for (int mt = 0; mt < 4; ++mt) {
        b1f[mt] = *(const f32x4*)(b1 + 16 * mt + 4 * lrow);
        b2f[mt] = *(const f32x4*)(b2 + 16 * mt + 4 * lrow);
    }
    const float b3s0 = b3[0], b3s1 = b3[1], b3s2 = b3[2];
    s16x8 localB[2];
    {
        const float* gs[4] = {g0, g1, g2, g3};
        const int    gn[4] = {32, 64, 128, 256};
        const int px = p & 255;
        const int py = p >> 8;
#pragma unroll
        for (int lv = 0; lv < 4; ++lv) {
            const int G = gn[lv];
            const float ix = (float)((2 * px + 1) * (G - 1)) * (1.0f / 512.0f);
            const float iy = (float)((2 * py + 1) * (G - 1)) * (1.0f / 512.0f);
            int ix0 = (int)ix;
            int iy0 = (int)iy;
            if (ix0 > G - 1) ix0 = G - 1;
            if (iy0 > G - 1) iy0 = G - 1;
            const int ix1 = (ix0 + 1 < G - 1) ? (ix0 + 1) : (G - 1);
            const int iy1 = (iy0 + 1 < G - 1) ? (iy0 + 1) : (G - 1);
            const float wx = ix - (float)ix0;
            const float wy = iy - (float)iy0;
            const float w00 = (1.0f - wy) * (1.0f - wx);
            const float w01 = (1.0f - wy) * wx;
            const float w10 = wy * (1.0f - wx);
            const float w11 = wy * wx;
            const int o00 = iy0 * G + ix0;
            const int o01 = iy0 * G + ix1;
            const int o10 = iy1 * G + ix0;
            const int o11 = iy1 * G + ix1;
            const float* g = gs[lv];
            const int GG = G * G;
#pragma unroll
            for (int j = 0; j < 4; ++j) {
                const float* gc = g + (4 * lrow + j) * GG;
                const float v = gc[o00] * w00 + gc[o01] * w01 +
                                gc[o10] * w10 + gc[o11] * w11;
                localB[lv >> 1][(lv & 1) * 4 + j] = bfbits(v);
            }
        }
    }
    __syncthreads();
    const short* lw = lds_w + lane * 8;
#define LDSFRAG(fid) (*(const s16x8*)(lw + (fid) * 64 * 8))
    s16x8 w1ff[4], w3f[2];
#pragma unroll
    for (int mt = 0; mt < 4; ++mt) w1ff[mt] = LDSFRAG(mt * 3);
    w3f[0] = LDSFRAG(20);
    w3f[1] = LDSFRAG(21);
    f32x4 c1base[4];
#pragma unroll
    for (int mt = 0; mt < 4; ++mt) {
        c1base[mt] = b1f[mt];
        c1base[mt] = MFMA16(LDSFRAG(mt * 3 + 1), localB[0], c1base[mt]);
        c1base[mt] = MFMA16(LDSFRAG(mt * 3 + 2), localB[1], c1base[mt]);
    }
    auto process = [&](int b, const s16x8 ff) {
        f32x4 c1[4];
#pragma unroll
        for (int mt = 0; mt < 4; ++mt)
            c1[mt] = MFMA16(w1ff[mt], ff, c1base[mt]);
        s16x8 h1b0 = pack_relu(c1[0], c1[1]);
        s16x8 h1b1 = pack_relu(c1[2], c1[3]);
        f32x4 c2[4];
#pragma unroll
        for (int mt = 0; mt < 4; ++mt) {
            c2[mt] = b2f[mt];
            c2[mt] = MFMA16(LDSFRAG(12 + mt * 2),     h1b0, c2[mt]);
            c2[mt] = MFMA16(LDSFRAG(12 + mt * 2 + 1), h1b1, c2[mt]);
        }
        s16x8 h2b0 = pack_relu(c2[0], c2[1]);
        s16x8 h2b1 = pack_relu(c2[2], c2[3]);
        f32x4 c3 = {0.f, 0.f, 0.f, 0.f};
        c3 = MFMA16(w3f[0], h2b0, c3);
        c3 = MFMA16(w3f[1], h2b1, c3);
        if (lrow == 0) {
            out[((b * 3 + 0) << 16) + p] = c3[0] + b3s0;
            out[((b * 3 + 1) << 16) + p] = c3[1] + b3s1;
            out[((b * 3 + 2) << 16) + p] = c3[2] + b3s2;
        }
    };
    float rawP[8], rawQ[8];
#pragma unroll
    for (int e = 0; e < 8; ++e) {
        const int fc = 4 * lrow + (e & 3) + 16 * (e >> 2);
        rawP[e] = feat[(fc << 16) + p];
        rawQ[e] = feat[((32 + fc) << 16) + p];
    }
#pragma unroll 1
    for (int bp = 0; bp < 4; ++bp) {
        s16x8 ff;
#pragma unroll
        for (int e = 0; e < 8; ++e) ff[e] = bfbits(rawP[e]);
        if (bp < 3) {
#pragma unroll
            for (int e = 0; e < 8; ++e) {
                const int fc = 4 * lrow + (e & 3) + 16 * (e >> 2);
                rawP[e] = feat[((((2 * bp + 2) << 5) | fc) << 16) + p];
            }
        }
        process(2 * bp, ff);
#pragma unroll
        for (int e = 0; e < 8; ++e) ff[e] = bfbits(rawQ[e]);
        if (bp < 3) {
#pragma unroll
            for (int e = 0; e < 8; ++e) {
                const int fc = 4 * lrow + (e & 3) + 16 * (e >> 2);
                rawQ[e] = feat[((((2 * bp + 3) << 5) | fc) << 16) + p];
            }
        }
        process(2 * bp + 1, ff);
    }
#undef LDSFRAG
}

extern "C" void kernel_launch(void* const* d_in, const int* in_sizes, int n_in,
                              void* d_out, int out_size, void* d_ws, size_t ws_size,
                              hipStream_t stream) {
    const float* feat = (const float*)d_in[0];
    const float* g0   = (const float*)d_in[1];
    const float* g1   = (const float*)d_in[2];
    const float* g2   = (const float*)d_in[3];
    const float* g3   = (const float*)d_in[4];
    const float* w1   = (const float*)d_in[5];
    const float* b1   = (const float*)d_in[6];
    const float* w2   = (const float*)d_in[7];
    const float* b2   = (const float*)d_in[8];
    const float* w3   = (const float*)d_in[9];
    const float* b3   = (const float*)d_in[10];

    const size_t need = (size_t)WS_TAB_BYTES + (size_t)16 * 65536 * 16;
    if (ws_size >= need) {
        k1_precomp<<<1024, 256, 0, stream>>>(g0, g1, g2, g3, w1, b1, w2, w3, d_ws);
        dim3 g2grid(1024, 4);   // 4096 blocks x 2 batches
        k2_mlp<<<g2grid, 256, 0, stream>>>(feat, b2, b3, d_ws, (float*)d_out);
    } else {
        grid_inr_r6<<<1024, 256, 0, stream>>>(
            feat, g0, g1, g2, g3, w1, b1, w2, b2, w3, b3, (float*)d_out);
    }
}

// Round 13
// 39.333 us; speedup vs baseline: 3.0999x; 1.5179x over previous
//
#include <hip/hip_runtime.h>
#include <hip/hip_bf16.h>

// Grid_INR2D round 13: two-kernel split, K2 on a strict register diet.
//  Round 12's K2 collapsed (VGPR 40, 57MB spill): 48 regs of up-front load
//  state + 2-batch body exceeded the (256,6) cap. Fix: ONE batch per block
//  (grid 1024x8), same load-early structure but minimal live set:
//  pre-barrier peak ~48 (table16+c1base16+raw8+addr), post-barrier ~50.
//  (256,6) cap~85 -> ~30 regs slack -> 6 resident blocks/CU = 6 waves/SIMD
//  (+50% TLP vs round 6's 4). Costs: table re-staged per block (L2-served),
//  c1base read per batch-slice (L3-served).
//  K1 unchanged (clean in r12). Round-6 fused kernel kept as ws fallback.
//  Same bf16 values + MFMA order -> absmax must stay exactly 0.0078125.
//  GATE: K2 VGPR<=48 AND WRITE>>7MB = collapse -> revert to round 6, stop.
// Fragment identity (validated rounds 3-12):
//   A: row=lane&15, k=4*(lane>>4)+(e&3)+16*(e>>2); B: col=lane&15, same k;
//   C/D: col=lane&15, row=4*(lane>>4)+reg  ==> C-frag of layer n is B-frag
//   of layer n+1 per-lane: B[kb].e = bf16(relu(C[2kb+(e>=4)].reg[e&3])).

typedef float f32x4 __attribute__((ext_vector_type(4)));
typedef short s16x8 __attribute__((ext_vector_type(8)));

#define MFMA16(a, b, c) __builtin_amdgcn_mfma_f32_16x16x32_bf16((a), (b), (c), 0, 0, 0)

__device__ __forceinline__ short bfbits(float f) {   // RNE via HW cvt
    return __builtin_bit_cast(short, __float2bfloat16(f));
}

__device__ __forceinline__ s16x8 pack_relu(const f32x4 lo, const f32x4 hi) {
    s16x8 r;
#pragma unroll
    for (int e = 0; e < 4; ++e) {
        r[e]     = bfbits(fmaxf(lo[e], 0.0f));
        r[e + 4] = bfbits(fmaxf(hi[e], 0.0f));
    }
    return r;
}

// ws layout: [0, 16384) bf16 frag table (14 frags x 1KB, padded to 16KB);
//            [16384, 16384+16MB) c1base, f32x4 granule (mt*4+lrow)*65536+p.
#define WS_TAB_BYTES 16384
#define NFRAG 14
// frag table ids: 0..3 = w1-feat[mt], 4..11 = w2[2mt+kb], 12..13 = w3[kb]

// ---------------------------------------------------------------- kernel 1
__global__ __launch_bounds__(256, 4) void k1_precomp(
    const float* __restrict__ g0, const float* __restrict__ g1,
    const float* __restrict__ g2, const float* __restrict__ g3,
    const float* __restrict__ w1, const float* __restrict__ b1,
    const float* __restrict__ w2, const float* __restrict__ w3,
    void* __restrict__ ws)
{
    const int lane  = threadIdx.x & 63;
    const int col   = lane & 15;
    const int lrow  = lane >> 4;
    const int wv    = threadIdx.x >> 6;
    const int p     = blockIdx.x * 64 + wv * 16 + col;

    // ---- block 0: build the pre-swizzled bf16 weight frag table in ws ----
    if (blockIdx.x == 0) {
        short* wtab = (short*)ws;
#pragma unroll 1
        for (int i = threadIdx.x; i < NFRAG * 64; i += 256) {
            const int fid = i >> 6, l = i & 63;
            const int c15 = l & 15, r4 = l >> 4;
            const float* src;
            if (fid < 4) {                       // w1-feat (kb=0 slice)
                src = w1 + (16 * fid + c15) * 96 + 4 * r4;
            } else if (fid < 12) {               // w2
                const int f = fid - 4, mt = f >> 1, kb = f & 1;
                src = w2 + (16 * mt + c15) * 64 + 32 * kb + 4 * r4;
            } else {                             // w3 (rows 3..15 junk)
                const int kb = fid - 12;
                const int row3 = (c15 < 3) ? c15 : 2;
                src = w3 + row3 * 64 + 32 * kb + 4 * r4;
            }
            s16x8 frag;
#pragma unroll
            for (int e = 0; e < 8; ++e)
                frag[e] = bfbits(src[(e & 3) + 16 * (e >> 2)]);
            *(s16x8*)&wtab[i * 8] = frag;
        }
    }

    // ---- grid-sample -> localB[2] (B-frags) -------------------------------
    s16x8 localB[2];
    {
        const float* gs[4] = {g0, g1, g2, g3};
        const int    gn[4] = {32, 64, 128, 256};
        const int px = p & 255;
        const int py = p >> 8;
#pragma unroll
        for (int lv = 0; lv < 4; ++lv) {
            const int G = gn[lv];
            const float ix = (float)((2 * px + 1) * (G - 1)) * (1.0f / 512.0f);
            const float iy = (float)((2 * py + 1) * (G - 1)) * (1.0f / 512.0f);
            int ix0 = (int)ix;
            int iy0 = (int)iy;
            if (ix0 > G - 1) ix0 = G - 1;
            if (iy0 > G - 1) iy0 = G - 1;
            const int ix1 = (ix0 + 1 < G - 1) ? (ix0 + 1) : (G - 1);
            const int iy1 = (iy0 + 1 < G - 1) ? (iy0 + 1) : (G - 1);
            const float wx = ix - (float)ix0;
            const float wy = iy - (float)iy0;
            const float w00 = (1.0f - wy) * (1.0f - wx);
            const float w01 = (1.0f - wy) * wx;
            const float w10 = wy * (1.0f - wx);
            const float w11 = wy * wx;
            const int o00 = iy0 * G + ix0;
            const int o01 = iy0 * G + ix1;
            const int o10 = iy1 * G + ix0;
            const int o11 = iy1 * G + ix1;
            const float* g = gs[lv];
            const int GG = G * G;
#pragma unroll
            for (int j = 0; j < 4; ++j) {
                const float* gc = g + (4 * lrow + j) * GG;
                const float v = gc[o00] * w00 + gc[o01] * w01 +
                                gc[o10] * w10 + gc[o11] * w11;
                localB[lv >> 1][(lv & 1) * 4 + j] = bfbits(v);
            }
        }
    }

    // ---- c1base[mt] = b1 + W1[:,32:96].local (w1-local frags transient) ----
    f32x4 c1base[4];
#pragma unroll
    for (int mt = 0; mt < 4; ++mt) {
        c1base[mt] = *(const f32x4*)(b1 + 16 * mt + 4 * lrow);
#pragma unroll
        for (int kb = 1; kb <= 2; ++kb) {
            const float* wr = w1 + (16 * mt + col) * 96 + 32 * kb + 4 * lrow;
            const f32x4 lo = *(const f32x4*)(wr);
            const f32x4 hi = *(const f32x4*)(wr + 16);
            s16x8 frag;
#pragma unroll
            for (int e = 0; e < 4; ++e) {
                frag[e]     = bfbits(lo[e]);
                frag[e + 4] = bfbits(hi[e]);
            }
            c1base[mt] = MFMA16(frag, localB[kb - 1], c1base[mt]);
        }
    }

    // ---- store c1base: 4 x (16 lanes x 16B = 256B coalesced) per wave ------
    f32x4* wsc = (f32x4*)((char*)ws + WS_TAB_BYTES);
#pragma unroll
    for (int mt = 0; mt < 4; ++mt)
        wsc[(mt * 4 + lrow) * 65536 + p] = c1base[mt];
}

// ---------------------------------------------------------------- kernel 2
// ONE batch per block; minimal live set; (256,6) with ~30 regs of slack.
__global__ __launch_bounds__(256, 6) void k2_mlp(
    const float* __restrict__ feat,
    const float* __restrict__ b2, const float* __restrict__ b3,
    const void* __restrict__ ws, float* __restrict__ out)
{
    __shared__ __align__(16) short lds_w[WS_TAB_BYTES / 2];

    const int lane  = threadIdx.x & 63;
    const int col   = lane & 15;
    const int lrow  = lane >> 4;
    const int wv    = threadIdx.x >> 6;
    const int p     = blockIdx.x * 64 + wv * 16 + col;
    const int b     = blockIdx.y;              // single batch for this block

    // issue table loads first (16 regs, die at ds_write)
    const f32x4* wtab = (const f32x4*)ws;
    const f32x4 s0 = wtab[threadIdx.x];
    const f32x4 s1 = wtab[threadIdx.x + 256];
    const f32x4 s2 = wtab[threadIdx.x + 512];
    const f32x4 s3 = wtab[threadIdx.x + 768];

    // c1base + this batch's feat (independent of LDS; overlap the barrier)
    const f32x4* wsc = (const f32x4*)((const char*)ws + WS_TAB_BYTES);
    f32x4 c1base[4];
#pragma unroll
    for (int mt = 0; mt < 4; ++mt)
        c1base[mt] = wsc[(mt * 4 + lrow) * 65536 + p];

    float raw[8];
#pragma unroll
    for (int e = 0; e < 8; ++e) {
        const int fc = 4 * lrow + (e & 3) + 16 * (e >> 2);
        raw[e] = feat[(((b << 5) | fc) << 16) + p];
    }
    const float b3s0 = b3[0], b3s1 = b3[1], b3s2 = b3[2];  // uniform s_loads

    // stage table to LDS (linear, coalesced)
    f32x4* lw4 = (f32x4*)lds_w;
    lw4[threadIdx.x]       = s0;
    lw4[threadIdx.x + 256] = s1;
    lw4[threadIdx.x + 512] = s2;
    lw4[threadIdx.x + 768] = s3;
    __syncthreads();

    const short* lwp = lds_w + lane * 8;
#define LDSFRAG(fid) (*(const s16x8*)(lwp + (fid) * 64 * 8))

    // ---------------- single-batch MLP body ---------------------------------
    s16x8 ff;
#pragma unroll
    for (int e = 0; e < 8; ++e) ff[e] = bfbits(raw[e]);

    f32x4 c1[4];
#pragma unroll
    for (int mt = 0; mt < 4; ++mt)
        c1[mt] = MFMA16(LDSFRAG(mt), ff, c1base[mt]);
    const s16x8 h1b0 = pack_relu(c1[0], c1[1]);
    const s16x8 h1b1 = pack_relu(c1[2], c1[3]);

    f32x4 c2[4];
#pragma unroll
    for (int mt = 0; mt < 4; ++mt) {
        c2[mt] = *(const f32x4*)(b2 + 16 * mt + 4 * lrow);
        c2[mt] = MFMA16(LDSFRAG(4 + mt * 2),     h1b0, c2[mt]);
        c2[mt] = MFMA16(LDSFRAG(4 + mt * 2 + 1), h1b1, c2[mt]);
    }
    const s16x8 h2b0 = pack_relu(c2[0], c2[1]);
    const s16x8 h2b1 = pack_relu(c2[2], c2[3]);

    f32x4 c3 = {0.f, 0.f, 0.f, 0.f};
    c3 = MFMA16(LDSFRAG(12), h2b0, c3);
    c3 = MFMA16(LDSFRAG(13), h2b1, c3);

    if (lrow == 0) {
        out[((b * 3 + 0) << 16) + p] = c3[0] + b3s0;
        out[((b * 3 + 1) << 16) + p] = c3[1] + b3s1;
        out[((b * 3 + 2) << 16) + p] = c3[2] + b3s2;
    }
#undef LDSFRAG
}

// ------------------------------------------- fallback: round-6 kernel (28.8us)
#define R6NFRAG 22
__global__ __launch_bounds__(256, 4) void grid_inr_r6(
    const float* __restrict__ feat,
    const float* __restrict__ g0, const float* __restrict__ g1,
    const float* __restrict__ g2, const float* __restrict__ g3,
    const float* __restrict__ w1, const float* __restrict__ b1,
    const float* __restrict__ w2, const float* __restrict__ b2,
    const float* __restrict__ w3, const float* __restrict__ b3,
    float* __restrict__ out)
{
    __shared__ __align__(16) short lds_w[R6NFRAG * 64 * 8];
    const int lane  = threadIdx.x & 63;
    const int col   = lane & 15;
    const int lrow  = lane >> 4;
    const int wv    = threadIdx.x >> 6;
    const int p     = blockIdx.x * 64 + wv * 16 + col;
    {
        const int cs = lane, c15 = lane & 15, r4 = lane >> 4;
#pragma unroll 1
        for (int fid = threadIdx.x >> 6; fid < R6NFRAG; fid += 4) {
            const float* src;
            if (fid < 12) {
                const int mt = fid / 3, kb = fid - 3 * mt;
                src = w1 + (16 * mt + c15) * 96 + 32 * kb + 4 * r4;
            } else if (fid < 20) {
                const int f = fid - 12, mt = f >> 1, kb = f & 1;
                src = w2 + (16 * mt + c15) * 64 + 32 * kb + 4 * r4;
            } else {
                const int kb = fid - 20;
                const int row3 = (c15 < 3) ? c15 : 2;
                src = w3 + row3 * 64 + 32 * kb + 4 * r4;
            }
            s16x8 frag;
#pragma unroll
            for (int e = 0; e < 8; ++e)
                frag[e] = bfbits(src[(e & 3) + 16 * (e >> 2)]);
            *(s16x8*)&lds_w[(fid * 64 + cs) * 8] = frag;
        }
    }
    f32x4 b1f[4], b2f[4];
#pragma unroll
    for (int mt = 0; mt < 4; ++mt) {
        b1f[mt] = *(const f32x4*)(b1 + 16 * mt + 4 * lrow);
        b2f[mt] = *(const f32x4*)(b2 + 16 * mt + 4 * lrow);
    }
    const float b3s0 = b3[0], b3s1 = b3[1], b3s2 = b3[2];
    s16x8 localB[2];
    {
        const float* gs[4] = {g0, g1, g2, g3};
        const int    gn[4] = {32, 64, 128, 256};
        const int px = p & 255;
        const int py = p >> 8;
#pragma unroll
        for (int lv = 0; lv < 4; ++lv) {
            const int G = gn[lv];
            const float ix = (float)((2 * px + 1) * (G - 1)) * (1.0f / 512.0f);
            const float iy = (float)((2 * py + 1) * (G - 1)) * (1.0f / 512.0f);
            int ix0 = (int)ix;
            int iy0 = (int)iy;
            if (ix0 > G - 1) ix0 = G - 1;
            if (iy0 > G - 1) iy0 = G - 1;
            const int ix1 = (ix0 + 1 < G - 1) ? (ix0 + 1) : (G - 1);
            const int iy1 = (iy0 + 1 < G - 1) ? (iy0 + 1) : (G - 1);
            const float wx = ix - (float)ix0;
            const float wy = iy - (float)iy0;
            const float w00 = (1.0f - wy) * (1.0f - wx);
            const float w01 = (1.0f - wy) * wx;
            const float w10 = wy * (1.0f - wx);
            const float w11 = wy * wx;
            const int o00 = iy0 * G + ix0;
            const int o01 = iy0 * G + ix1;
            const int o10 = iy1 * G + ix0;
            const int o11 = iy1 * G + ix1;
            const float* g = gs[lv];
            const int GG = G * G;
#pragma unroll
            for (int j = 0; j < 4; ++j) {
                const float* gc = g + (4 * lrow + j) * GG;
                const float v = gc[o00] * w00 + gc[o01] * w01 +
                                gc[o10] * w10 + gc[o11] * w11;
                localB[lv >> 1][(lv & 1) * 4 + j] = bfbits(v);
            }
        }
    }
    __syncthreads();
    const short* lw = lds_w + lane * 8;
#define LDSFRAG(fid) (*(const s16x8*)(lw + (fid) * 64 * 8))
    s16x8 w1ff[4], w3f[2];
#pragma unroll
    for (int mt = 0; mt < 4; ++mt) w1ff[mt] = LDSFRAG(mt * 3);
    w3f[0] = LDSFRAG(20);
    w3f[1] = LDSFRAG(21);
    f32x4 c1base[4];
#pragma unroll
    for (int mt = 0; mt < 4; ++mt) {
        c1base[mt] = b1f[mt];
        c1base[mt] = MFMA16(LDSFRAG(mt * 3 + 1), localB[0], c1base[mt]);
        c1base[mt] = MFMA16(LDSFRAG(mt * 3 + 2), localB[1], c1base[mt]);
    }
    auto process = [&](int b, const s16x8 ff) {
        f32x4 c1[4];
#pragma unroll
        for (int mt = 0; mt < 4; ++mt)
            c1[mt] = MFMA16(w1ff[mt], ff, c1base[mt]);
        s16x8 h1b0 = pack_relu(c1[0], c1[1]);
        s16x8 h1b1 = pack_relu(c1[2], c1[3]);
        f32x4 c2[4];
#pragma unroll
        for (int mt = 0; mt < 4; ++mt) {
            c2[mt] = b2f[mt];
            c2[mt] = MFMA16(LDSFRAG(12 + mt * 2),     h1b0, c2[mt]);
            c2[mt] = MFMA16(LDSFRAG(12 + mt * 2 + 1), h1b1, c2[mt]);
        }
        s16x8 h2b0 = pack_relu(c2[0], c2[1]);
        s16x8 h2b1 = pack_relu(c2[2], c2[3]);
        f32x4 c3 = {0.f, 0.f, 0.f, 0.f};
        c3 = MFMA16(w3f[0], h2b0, c3);
        c3 = MFMA16(w3f[1], h2b1, c3);
        if (lrow == 0) {
            out[((b * 3 + 0) << 16) + p] = c3[0] + b3s0;
            out[((b * 3 + 1) << 16) + p] = c3[1] + b3s1;
            out[((b * 3 + 2) << 16) + p] = c3[2] + b3s2;
        }
    };
    float rawP[8], rawQ[8];
#pragma unroll
    for (int e = 0; e < 8; ++e) {
        const int fc = 4 * lrow + (e & 3) + 16 * (e >> 2);
        rawP[e] = feat[(fc << 16) + p];
        rawQ[e] = feat[((32 + fc) << 16) + p];
    }
#pragma unroll 1
    for (int bp = 0; bp < 4; ++bp) {
        s16x8 ff;
#pragma unroll
        for (int e = 0; e < 8; ++e) ff[e] = bfbits(rawP[e]);
        if (bp < 3) {
#pragma unroll
            for (int e = 0; e < 8; ++e) {
                const int fc = 4 * lrow + (e & 3) + 16 * (e >> 2);
                rawP[e] = feat[((((2 * bp + 2) << 5) | fc) << 16) + p];
            }
        }
        process(2 * bp, ff);
#pragma unroll
        for (int e = 0; e < 8; ++e) ff[e] = bfbits(rawQ[e]);
        if (bp < 3) {
#pragma unroll
            for (int e = 0; e < 8; ++e) {
                const int fc = 4 * lrow + (e & 3) + 16 * (e >> 2);
                rawQ[e] = feat[((((2 * bp + 3) << 5) | fc) << 16) + p];
            }
        }
        process(2 * bp + 1, ff);
    }
#undef LDSFRAG
}

extern "C" void kernel_launch(void* const* d_in, const int* in_sizes, int n_in,
                              void* d_out, int out_size, void* d_ws, size_t ws_size,
                              hipStream_t stream) {
    const float* feat = (const float*)d_in[0];
    const float* g0   = (const float*)d_in[1];
    const float* g1   = (const float*)d_in[2];
    const float* g2   = (const float*)d_in[3];
    const float* g3   = (const float*)d_in[4];
    const float* w1   = (const float*)d_in[5];
    const float* b1   = (const float*)d_in[6];
    const float* w2   = (const float*)d_in[7];
    const float* b2   = (const float*)d_in[8];
    const float* w3   = (const float*)d_in[9];
    const float* b3   = (const float*)d_in[10];

    const size_t need = (size_t)WS_TAB_BYTES + (size_t)16 * 65536 * 16;
    if (ws_size >= need) {
        k1_precomp<<<1024, 256, 0, stream>>>(g0, g1, g2, g3, w1, b1, w2, w3, d_ws);
        dim3 g2grid(1024, 8);   // 8192 blocks x 1 batch
        k2_mlp<<<g2grid, 256, 0, stream>>>(feat, b2, b3, d_ws, (float*)d_out);
    } else {
        grid_inr_r6<<<1024, 256, 0, stream>>>(
            feat, g0, g1, g2, g3, w1, b1, w2, b2, w3, b3, (float*)d_out);
    }
}

// Round 14
// 28.753 us; speedup vs baseline: 4.2405x; 1.3679x over previous
//
#include <hip/hip_runtime.h>
#include <hip/hip_bf16.h>

// Grid_INR2D FINAL (round 14 = round 6 verbatim, 28.8us verified).
//  Best measured configuration: fused single kernel, bf16-MFMA chain,
//  weights as pre-swizzled LDS frag table, batch-invariant c1base hoist,
//  w1-feat/w3 reg-cached, 2-deep feat prefetch, (256,4), 1024 blocks.
//  Rounds 7-13 post-mortems (all regressed): ILP-doubling and pipeline
//  variants collapse the register allocator (VGPR 64/48/40/32 + scratch
//  spill) -- the body has zero slack at the 128-VGPR/(256,4) point; a
//  two-kernel split avoids the wall but its data-movement overhead
//  (c1base round-trip + table re-staging) exceeds the TLP gain.
//  Remaining gap to the ~12us HBM floor is MLP dependency-chain latency;
//  hiding it needs in-flight state the allocator won't grant at HIP level.
// Fragment identity (validated rounds 3-13):
//   A: row=lane&15, k=4*(lane>>4)+(e&3)+16*(e>>2); B: col=lane&15, same k;
//   C/D: col=lane&15, row=4*(lane>>4)+reg  ==> C-frag of layer n is B-frag
//   of layer n+1 per-lane: B[kb].e = bf16(relu(C[2kb+(e>=4)].reg[e&3])).

typedef float f32x4 __attribute__((ext_vector_type(4)));
typedef short s16x8 __attribute__((ext_vector_type(8)));

#define MFMA16(a, b, c) __builtin_amdgcn_mfma_f32_16x16x32_bf16((a), (b), (c), 0, 0, 0)

__device__ __forceinline__ short bfbits(float f) {   // RNE via HW cvt
    return __builtin_bit_cast(short, __float2bfloat16(f));
}

__device__ __forceinline__ s16x8 pack_relu(const f32x4 lo, const f32x4 hi) {
    s16x8 r;
#pragma unroll
    for (int e = 0; e < 4; ++e) {
        r[e]     = bfbits(fmaxf(lo[e], 0.0f));
        r[e + 4] = bfbits(fmaxf(hi[e], 0.0f));
    }
    return r;
}

// LDS frag table: fid 0..11 = w1[mt*3+kb], 12..19 = w2[mt*2+kb], 20..21 = w3[kb]
#define NFRAG 22

__global__ __launch_bounds__(256, 4) void grid_inr_mfma(
    const float* __restrict__ feat,
    const float* __restrict__ g0, const float* __restrict__ g1,
    const float* __restrict__ g2, const float* __restrict__ g3,
    const float* __restrict__ w1, const float* __restrict__ b1,
    const float* __restrict__ w2, const float* __restrict__ b2,
    const float* __restrict__ w3, const float* __restrict__ b3,
    float* __restrict__ out)
{
    __shared__ __align__(16) short lds_w[NFRAG * 64 * 8];

    const int lane  = threadIdx.x & 63;
    const int col   = lane & 15;    // A row / B col / pixel-in-tile
    const int lrow  = lane >> 4;    // k-group
    const int wv    = threadIdx.x >> 6;
    const int p     = blockIdx.x * 64 + wv * 16 + col;   // this lane's pixel

    // ---------------- stage weight A-frags into LDS (once per block) -------
    {
        const int cs = lane, c15 = lane & 15, r4 = lane >> 4;
#pragma unroll 1
        for (int fid = threadIdx.x >> 6; fid < NFRAG; fid += 4) {
            const float* src;
            if (fid < 12) {
                const int mt = fid / 3, kb = fid - 3 * mt;
                src = w1 + (16 * mt + c15) * 96 + 32 * kb + 4 * r4;
            } else if (fid < 20) {
                const int f = fid - 12, mt = f >> 1, kb = f & 1;
                src = w2 + (16 * mt + c15) * 64 + 32 * kb + 4 * r4;
            } else {
                const int kb = fid - 20;
                const int row3 = (c15 < 3) ? c15 : 2;   // junk rows unused
                src = w3 + row3 * 64 + 32 * kb + 4 * r4;
            }
            s16x8 frag;
#pragma unroll
            for (int e = 0; e < 8; ++e)
                frag[e] = bfbits(src[(e & 3) + 16 * (e >> 2)]);
            *(s16x8*)&lds_w[(fid * 64 + cs) * 8] = frag;
        }
    }

    // ---------------- biases in regs (f32, per-lane rows) -------------------
    f32x4 b1f[4], b2f[4];
#pragma unroll
    for (int mt = 0; mt < 4; ++mt) {
        b1f[mt] = *(const f32x4*)(b1 + 16 * mt + 4 * lrow);
        b2f[mt] = *(const f32x4*)(b2 + 16 * mt + 4 * lrow);
    }
    const float b3s0 = b3[0], b3s1 = b3[1], b3s2 = b3[2];  // uniform s_loads

    // ---------------- grid-sample -> localB[2] (B-frags, k=local ch) --------
    s16x8 localB[2];
    {
        const float* gs[4] = {g0, g1, g2, g3};
        const int    gn[4] = {32, 64, 128, 256};
        const int px = p & 255;
        const int py = p >> 8;
#pragma unroll
        for (int lv = 0; lv < 4; ++lv) {
            const int G = gn[lv];
            const float ix = (float)((2 * px + 1) * (G - 1)) * (1.0f / 512.0f);
            const float iy = (float)((2 * py + 1) * (G - 1)) * (1.0f / 512.0f);
            int ix0 = (int)ix;
            int iy0 = (int)iy;
            if (ix0 > G - 1) ix0 = G - 1;
            if (iy0 > G - 1) iy0 = G - 1;
            const int ix1 = (ix0 + 1 < G - 1) ? (ix0 + 1) : (G - 1);
            const int iy1 = (iy0 + 1 < G - 1) ? (iy0 + 1) : (G - 1);
            const float wx = ix - (float)ix0;
            const float wy = iy - (float)iy0;
            const float w00 = (1.0f - wy) * (1.0f - wx);
            const float w01 = (1.0f - wy) * wx;
            const float w10 = wy * (1.0f - wx);
            const float w11 = wy * wx;
            const int o00 = iy0 * G + ix0;
            const int o01 = iy0 * G + ix1;
            const int o10 = iy1 * G + ix0;
            const int o11 = iy1 * G + ix1;
            const float* g = gs[lv];
            const int GG = G * G;
#pragma unroll
            for (int j = 0; j < 4; ++j) {
                const float* gc = g + (4 * lrow + j) * GG;
                const float v = gc[o00] * w00 + gc[o01] * w01 +
                                gc[o10] * w10 + gc[o11] * w11;
                localB[lv >> 1][(lv & 1) * 4 + j] = bfbits(v);
            }
        }
    }

    __syncthreads();   // LDS frag table ready

    const short* lw = lds_w + lane * 8;      // per-lane base; fid via offset
#define LDSFRAG(fid) (*(const s16x8*)(lw + (fid) * 64 * 8))

    // ---- register-cache small frag groups; hoist batch-invariant layer-1 ---
    s16x8 w1ff[4], w3f[2];
#pragma unroll
    for (int mt = 0; mt < 4; ++mt) w1ff[mt] = LDSFRAG(mt * 3);
    w3f[0] = LDSFRAG(20);
    w3f[1] = LDSFRAG(21);

    // c1base[mt] = b1 + W1[:,32:96] . local   (batch-invariant, once)
    f32x4 c1base[4];
#pragma unroll
    for (int mt = 0; mt < 4; ++mt) {
        c1base[mt] = b1f[mt];
        c1base[mt] = MFMA16(LDSFRAG(mt * 3 + 1), localB[0], c1base[mt]);
        c1base[mt] = MFMA16(LDSFRAG(mt * 3 + 2), localB[1], c1base[mt]);
    }

    // ---- per-batch MLP body (b only feeds store addressing) ----------------
    auto process = [&](int b, const s16x8 ff) {
        f32x4 c1[4];
#pragma unroll
        for (int mt = 0; mt < 4; ++mt)
            c1[mt] = MFMA16(w1ff[mt], ff, c1base[mt]);

        s16x8 h1b0 = pack_relu(c1[0], c1[1]);
        s16x8 h1b1 = pack_relu(c1[2], c1[3]);

        f32x4 c2[4];
#pragma unroll
        for (int mt = 0; mt < 4; ++mt) {
            c2[mt] = b2f[mt];
            c2[mt] = MFMA16(LDSFRAG(12 + mt * 2),     h1b0, c2[mt]);
            c2[mt] = MFMA16(LDSFRAG(12 + mt * 2 + 1), h1b1, c2[mt]);
        }
        s16x8 h2b0 = pack_relu(c2[0], c2[1]);
        s16x8 h2b1 = pack_relu(c2[2], c2[3]);

        f32x4 c3 = {0.f, 0.f, 0.f, 0.f};
        c3 = MFMA16(w3f[0], h2b0, c3);
        c3 = MFMA16(w3f[1], h2b1, c3);

        if (lrow == 0) {
            out[((b * 3 + 0) << 16) + p] = c3[0] + b3s0;
            out[((b * 3 + 1) << 16) + p] = c3[1] + b3s1;
            out[((b * 3 + 2) << 16) + p] = c3[2] + b3s2;
        }
    };

    // ---- batch loop: 2-deep feat prefetch via named ping-pong buffers ------
    float rawP[8], rawQ[8];
#pragma unroll
    for (int e = 0; e < 8; ++e) {
        const int fc = 4 * lrow + (e & 3) + 16 * (e >> 2);
        rawP[e] = feat[(fc << 16) + p];          // batch 0
        rawQ[e] = feat[((32 + fc) << 16) + p];   // batch 1
    }

#pragma unroll 1
    for (int bp = 0; bp < 4; ++bp) {
        // batch A = 2*bp (from rawP); refill rawP with batch 2*bp+2
        s16x8 ff;
#pragma unroll
        for (int e = 0; e < 8; ++e) ff[e] = bfbits(rawP[e]);
        if (bp < 3) {
#pragma unroll
            for (int e = 0; e < 8; ++e) {
                const int fc = 4 * lrow + (e & 3) + 16 * (e >> 2);
                rawP[e] = feat[((((2 * bp + 2) << 5) | fc) << 16) + p];
            }
        }
        process(2 * bp, ff);

        // batch B = 2*bp+1 (from rawQ); refill rawQ with batch 2*bp+3
#pragma unroll
        for (int e = 0; e < 8; ++e) ff[e] = bfbits(rawQ[e]);
        if (bp < 3) {
#pragma unroll
            for (int e = 0; e < 8; ++e) {
                const int fc = 4 * lrow + (e & 3) + 16 * (e >> 2);
                rawQ[e] = feat[((((2 * bp + 3) << 5) | fc) << 16) + p];
            }
        }
        process(2 * bp + 1, ff);
    }
#undef LDSFRAG
}

extern "C" void kernel_launch(void* const* d_in, const int* in_sizes, int n_in,
                              void* d_out, int out_size, void* d_ws, size_t ws_size,
                              hipStream_t stream) {
    const float* feat = (const float*)d_in[0];
    const float* g0   = (const float*)d_in[1];
    const float* g1   = (const float*)d_in[2];
    const float* g2   = (const float*)d_in[3];
    const float* g3   = (const float*)d_in[4];
    const float* w1   = (const float*)d_in[5];
    const float* b1   = (const float*)d_in[6];
    const float* w2   = (const float*)d_in[7];
    const float* b2   = (const float*)d_in[8];
    const float* w3   = (const float*)d_in[9];
    const float* b3   = (const float*)d_in[10];

    // 65536 px / (16 px/wave * 4 waves) = 1024 blocks; all 8 batches inside.
    grid_inr_mfma<<<1024, 256, 0, stream>>>(
        feat, g0, g1, g2, g3, w1, b1, w2, b2, w3, b3, (float*)d_out);
}